// Round 7
// baseline (70.224 us; speedup 1.0000x reference)
//
#include <hip/hip_runtime.h>

#define CIN 27
#define HH 64
#define WW 64
#define OC 32
#define TW 16            // tile width (pixels)
#define TH 16            // tile height (pixels)
#define RS 20            // LDS row stride (dwords), even -> all window reads are aligned b64
#define CS (18 * RS)     // 360 dwords per channel slab
#define WS 12            // padded per-channel weight stride (48B, 16B-aligned)
// LDS: 27*360*4 + 27*12*4 = 40176 B <= 40960 -> exactly 4 blocks/CU (LDS-capped)

__device__ __forceinline__ float maj3(float a, float b, float c) {
    // Exact closed form of bipolar 3-input majority gate: (a + b + c - a*b*c)/2
    float s = a + b + c;
    return 0.5f * fmaf(-(a * b), c, s);
}

__device__ __forceinline__ float2 pk_maj3(float2 a, float2 b, float2 c) {
    float2 r;
    r.x = maj3(a.x, b.x, c.x);
    r.y = maj3(a.y, b.y, c.y);
    return r;
}

__global__ __launch_bounds__(128) void sconv_maj_kernel(
    const float* __restrict__ x,    // [N, CIN, 64, 64]
    const float* __restrict__ wgt,  // [OC, CIN, 3, 3]
    float* __restrict__ out)        // [N, OC, 64, 64]
{
    __shared__ __align__(16) float sw[CIN * WS];
    __shared__ __align__(16) float sx[CIN * CS];

    const int tx = threadIdx.x;            // 0..7  (pixel cols 2tx, 2tx+1)
    const int ty = threadIdx.y;            // 0..15
    const int tid = ty * 8 + tx;
    const int tile_w0 = blockIdx.x * TW;
    const int tile_h0 = blockIdx.y * TH;
    const int n  = blockIdx.z >> 5;        // OC = 32
    const int oc = blockIdx.z & 31;

    // ---- stage weights (block-uniform oc) into padded LDS slots ----
    for (int i = tid; i < CIN * 9; i += 128) {
        int c = i / 9;
        int k = i - 9 * c;
        sw[c * WS + k] = wgt[oc * (CIN * 9) + i];
    }

    // ---- stage x tile with 1-halo (single pass, all 27 channels) ----
    const float* xn = x + (size_t)n * (CIN * HH * WW);
    for (int pos = tid; pos < 18 * 18; pos += 128) {
        int r   = pos / 18;
        int col = pos - 18 * r;
        int gr = tile_h0 + r - 1;
        int gc = tile_w0 + col - 1;
        bool ok = ((unsigned)gr < (unsigned)HH) & ((unsigned)gc < (unsigned)WW);
        int off = ok ? (gr * WW + gc) : 0;     // clamped addr, select after load
        float* lp = sx + r * RS + col;
        #pragma unroll
        for (int c = 0; c < CIN; ++c) {
            float raw = xn[(size_t)c * (HH * WW) + off];
            lp[c * CS] = ok ? raw : 0.0f;
        }
    }
    __syncthreads();

    // ---- 5-level majority tree; channels processed in groups of 3 with an
    // explicit batched LOAD phase (27 independent lgkm events in flight) then
    // a pure-register COMPUTE phase. This is the overlap-hypothesis test:
    // exposed ds_read latency per group ~1x120cyc instead of ~27x120cyc. ----
    float2 m4[3];
    #pragma unroll
    for (int q = 0; q < 3; ++q) {              // level-4 group (9 channels)
        float2 m3[3];
        #pragma unroll
        for (int t = 0; t < 3; ++t) {          // level-3 group (3 channels)
            const int cbase = q * 9 + t * 3;

            // ---- load phase: 18 ds_read_b64 (x) + 9 weight reads ----
            float2 xv[3][3][2];                // [u][ki][half]
            float4 wv[3][3];                   // [u][quad]; only first 9 lanes used
            #pragma unroll
            for (int u = 0; u < 3; ++u) {
                const int c = cbase + u;
                const float* base = &sx[c * CS + ty * RS + 2 * tx];
                #pragma unroll
                for (int ki = 0; ki < 3; ++ki) {
                    const float2* prow = (const float2*)(base + ki * RS);
                    xv[u][ki][0] = prow[0];    // cols 2tx, 2tx+1
                    xv[u][ki][1] = prow[1];    // cols 2tx+2, 2tx+3
                }
                wv[u][0] = *(const float4*)&sw[c * WS];       // w0..w3
                wv[u][1] = *(const float4*)&sw[c * WS + 4];   // w4..w7
                wv[u][2] = *(const float4*)&sw[c * WS + 8];   // w8 (+pad, unused)
            }
            // Pin the batch: nothing from the compute phase may hoist above,
            // no load may sink below.
            __builtin_amdgcn_sched_barrier(0);

            // ---- compute phase: registers only ----
            float2 m2[3];
            #pragma unroll
            for (int u = 0; u < 3; ++u) {
                const float wk[9] = {wv[u][0].x, wv[u][0].y, wv[u][0].z, wv[u][0].w,
                                     wv[u][1].x, wv[u][1].y, wv[u][1].z, wv[u][1].w,
                                     wv[u][2].x};
                float2 m1[3];
                #pragma unroll
                for (int ki = 0; ki < 3; ++ki) {
                    float2 v01 = xv[u][ki][0];
                    float2 v23 = xv[u][ki][1];
                    float w0 = wk[ki * 3 + 0];
                    float w1 = wk[ki * 3 + 1];
                    float w2 = wk[ki * 3 + 2];
                    // pixel A (col 2tx): v01.x v01.y v23.x ; pixel B: v01.y v23.x v23.y
                    float2 p0 = make_float2(v01.x * w0, v01.y * w0);
                    float2 p1 = make_float2(v01.y * w1, v23.x * w1);
                    float2 p2 = make_float2(v23.x * w2, v23.y * w2);
                    m1[ki] = pk_maj3(p0, p1, p2);
                }
                m2[u] = pk_maj3(m1[0], m1[1], m1[2]);
            }
            m3[t] = pk_maj3(m2[0], m2[1], m2[2]);
        }
        m4[q] = pk_maj3(m3[0], m3[1], m3[2]);
    }
    float2 res = pk_maj3(m4[0], m4[1], m4[2]);

    const int h = tile_h0 + ty;
    const int w = tile_w0 + 2 * tx;
    float2* po = (float2*)(out + (((size_t)n * OC + oc) * HH + h) * WW + w);
    *po = res;
}

extern "C" void kernel_launch(void* const* d_in, const int* in_sizes, int n_in,
                              void* d_out, int out_size, void* d_ws, size_t ws_size,
                              hipStream_t stream) {
    const float* x   = (const float*)d_in[0];
    const float* wgt = (const float*)d_in[1];
    float* out = (float*)d_out;

    dim3 block(8, 16, 1);                 // 128 threads, 2 waves
    dim3 grid(WW / TW, HH / TH, 2 * OC);  // (4,4,64) = 1024 blocks, 4/CU, fully resident
    sconv_maj_kernel<<<grid, block, 0, stream>>>(x, wgt, out);
}